// Round 6
// baseline (300.465 us; speedup 1.0000x reference)
//
#include <hip/hip_runtime.h>
#include <hip/hip_cooperative_groups.h>

namespace cg = cooperative_groups;

// Ball query via 5x5x5 uniform grid + parallel counting sort + per-wave hit
// bitmap, fused into ONE cooperative kernel (grid.sync between phases).
// B=4, N1=2048 queries, N2=8192 keys, K=64, r=0.1 (cell = 0.2 = 2r, so a
// query ball overlaps at most a 2x2x2 octant of cells).
//
// Phases (1024 blocks x 256 thr, 4 blocks/CU co-resident):
//   A. blocks 0..127: per-256-key-sub-block LDS histogram -> hists[128][125]
//   B. blocks 0..127: redundant scan of own batch's 32 sub-hists (L2-hot) ->
//      cell starts + per-sub-block per-cell bases; scatter 256 keys via LDS
//      cursors into sorted[B][N2] float4{x,y,z,idx}. Disjoint ranges per
//      (sub,cell) => race-free, no global atomics.
//   C. all blocks: 2 queries per wave; scan <=4 contiguous (x,y)-column
//      z-runs, set bits in an 8192-bit LDS bitmap keyed by ORIGINAL key
//      index, extract first K set bits in order (exact key-order output,
//      even when >K hits).
//
// grid.sync() provides both the barrier and device-scope visibility for the
// cross-XCD hists/sorted handoffs. Fallbacks: 3-kernel pipeline if the
// cooperative launch is rejected; brute force if ws too small.

constexpr int   K    = 64;
constexpr float R2   = 0.01f;   // 0.1^2
constexpr int   B    = 4;
constexpr int   N1   = 2048;
constexpr int   N2   = 8192;
constexpr int   GC   = 5;                 // grid cells per dim
constexpr int   NCELL = GC * GC * GC;     // 125
constexpr float INVCELL = 5.0f;           // 1 / 0.2
constexpr int   SUBS       = 128;         // 256-key sub-blocks total (B*N2/256)
constexpr int   SUBS_PER_B = 32;          // per batch
constexpr int   GRID       = 1024;        // fused-kernel blocks (4 per CU)
constexpr int   QPW        = 2;           // queries per wave in phase C

// ---------------- workspace layout ----------------
constexpr size_t SORTED_BYTES = (size_t)B * N2 * 16;
constexpr size_t CS_BYTES     = (size_t)B * (NCELL + 1) * 4;
constexpr size_t WS_NEEDED    = SORTED_BYTES + CS_BYTES + (size_t)SUBS * NCELL * 4;

__device__ __forceinline__ int cell_of(float v) {
    int c = (int)(v * INVCELL);
    return c < 0 ? 0 : (c > GC - 1 ? GC - 1 : c);
}

// ---------------- shared phase bodies ----------------
__device__ __forceinline__ void hist_body(
    const float* __restrict__ key, int* __restrict__ hists,
    int blk, int t, int* h)
{
    if (t < NCELL) h[t] = 0;
    __syncthreads();
    const int p = blk * 256 + t;         // global key id
    const float x = key[p * 3 + 0];
    const float y = key[p * 3 + 1];
    const float z = key[p * 3 + 2];
    const int cell = (cell_of(x) * GC + cell_of(y)) * GC + cell_of(z);
    atomicAdd(&h[cell], 1);
    __syncthreads();
    if (t < NCELL) hists[blk * NCELL + t] = h[t];
}

__device__ __forceinline__ void scatter_body(
    const float* __restrict__ key, const int* __restrict__ hists,
    int* __restrict__ cell_start, float4* __restrict__ sorted,
    int blk, int t, int* sbuf, int* cursor)
{
    const int b = blk >> 5;              // batch
    const int s = blk & 31;              // sub index within batch

    int mybase = 0, total = 0;
    if (t < NCELL) {
        const int* hb = hists + (b * SUBS_PER_B) * NCELL + t;
        int acc = 0;
        #pragma unroll
        for (int s2 = 0; s2 < SUBS_PER_B; ++s2) {
            if (s2 == s) mybase = acc;
            acc += hb[s2 * NCELL];
        }
        total = acc;
    }

    if (t < 128) sbuf[t] = (t < NCELL) ? total : 0;
    __syncthreads();
    for (int off = 1; off < 128; off <<= 1) {
        int v = 0;
        if (t < 128 && t >= off) v = sbuf[t - off];
        __syncthreads();
        if (t < 128) sbuf[t] += v;
        __syncthreads();
    }
    if (t < NCELL) {
        const int excl = sbuf[t] - total;          // exclusive cell start
        cursor[t] = excl + mybase;                 // my sub-block's base in cell t
        if (s == 0) {                              // one writer per batch
            cell_start[b * (NCELL + 1) + t + 1] = sbuf[t];
            if (t == 0) cell_start[b * (NCELL + 1)] = 0;
        }
    }
    __syncthreads();

    const int p = blk * 256 + t;                   // global key id
    const float x = key[p * 3 + 0];
    const float y = key[p * 3 + 1];
    const float z = key[p * 3 + 2];
    const int cell = (cell_of(x) * GC + cell_of(y)) * GC + cell_of(z);
    const int pos  = atomicAdd(&cursor[cell], 1);  // LDS, block-local
    float4 v;
    v.x = x; v.y = y; v.z = z; v.w = __int_as_float(p & (N2 - 1));
    sorted[(size_t)b * N2 + pos] = v;
}

__device__ __forceinline__ void query_body(
    const float* __restrict__ query, const float4* __restrict__ sorted,
    const int* __restrict__ cell_start, int* __restrict__ out,
    int q, int lane, unsigned int* wbm)
{
    const int b = q >> 11;

    const float qx = query[q * 3 + 0];
    const float qy = query[q * 3 + 1];
    const float qz = query[q * 3 + 2];

    // Octant of cells the ball can touch (cell = 2r, so +/-1 on the near side).
    const float ux = qx * INVCELL, uy = qy * INVCELL, uz = qz * INVCELL;
    const int cx = cell_of(qx), cy = cell_of(qy), cz = cell_of(qz);
    const int nx = (ux - cx < 0.5f) ? cx - 1 : cx + 1;
    const int ny = (uy - cy < 0.5f) ? cy - 1 : cy + 1;
    const int nz = (uz - cz < 0.5f) ? cz - 1 : cz + 1;
    const int xlo = max(0, min(cx, nx)), xhi = min(GC - 1, max(cx, nx));
    const int ylo = max(0, min(cy, ny)), yhi = min(GC - 1, max(cy, ny));
    const int zlo = max(0, min(cz, nz)), zhi = min(GC - 1, max(cz, nz));

    uint4 zz; zz.x = zz.y = zz.z = zz.w = 0u;
    ((uint4*)wbm)[lane] = zz;               // clear bitmap (ds_write_b128)
    __threadfence_block();

    const int*    cs = cell_start + b * (NCELL + 1);
    const float4* sb = sorted + (size_t)b * N2;

    for (int xx = xlo; xx <= xhi; ++xx) {
        for (int yy = ylo; yy <= yhi; ++yy) {
            const int colz = (xx * GC + yy) * GC;
            const int s = cs[colz + zlo];
            const int e = cs[colz + zhi + 1];          // z-cells are contiguous
            for (int t0 = s; t0 < e; t0 += 64) {
                const int i = t0 + lane;
                const float4 kv = sb[min(i, e - 1)];
                const float dx = kv.x - qx;
                const float dy = kv.y - qy;
                const float dz = kv.z - qz;
                const bool within = (i < e) && (dx * dx + dy * dy + dz * dz < R2);
                if (within) {
                    const int id = __float_as_int(kv.w);
                    atomicOr(&wbm[id >> 5], 1u << (id & 31));
                }
            }
        }
    }
    __threadfence_block();

    // ---- extraction: lane owns original-index range [128*lane, 128*lane+128)
    const uint4 w = ((const uint4*)wbm)[lane];
    const int c = __popc(w.x) + __popc(w.y) + __popc(w.z) + __popc(w.w);

    int x = c;                               // inclusive wave prefix sum
    #pragma unroll
    for (int off = 1; off < 64; off <<= 1) {
        int y = __shfl_up(x, off);
        if (lane >= off) x += y;
    }
    const int base = x - c;
    const int cnt  = __shfl(x, 63);

    int fs;                                  // first set bit overall (0 if none)
    if      (w.x) fs = __builtin_ctz(w.x);
    else if (w.y) fs = 32 + __builtin_ctz(w.y);
    else if (w.z) fs = 64 + __builtin_ctz(w.z);
    else if (w.w) fs = 96 + __builtin_ctz(w.w);
    else          fs = 0;
    int myfirst = c ? (lane << 7) + fs : 0x7fffffff;
    #pragma unroll
    for (int off = 32; off; off >>= 1)
        myfirst = min(myfirst, __shfl_xor(myfirst, off));
    const int firstIdx = (cnt == 0) ? 0 : myfirst;

    int* op = out + q * K;                   // emit set bits in order
    int slot = base;
    unsigned int wr[4] = {w.x, w.y, w.z, w.w};
    #pragma unroll
    for (int r = 0; r < 4; ++r) {
        unsigned int m = wr[r];
        const int bb = (lane << 7) + (r << 5);
        while (m) {
            const int bp = __builtin_ctz(m);
            m &= m - 1;
            if (slot < K) op[slot] = bb + bp;
            ++slot;
        }
    }

    const int kpad = cnt < K ? cnt : K;      // pad with firstIdx
    const int s2 = kpad + lane;
    if (s2 < K) op[s2] = firstIdx;
}

// ---------------- fused cooperative kernel ----------------
__global__ __launch_bounds__(256, 4) void fused_kernel(
    const float* __restrict__ query, const float* __restrict__ key,
    int* __restrict__ out, int* __restrict__ hists,
    int* __restrict__ cell_start, float4* __restrict__ sorted)
{
    __shared__ unsigned int shmem[4 * 256];   // 4 KB, reused across phases
    cg::grid_group grid = cg::this_grid();

    const int blk  = blockIdx.x;
    const int t    = threadIdx.x;
    const int lane = t & 63;
    const int wv   = t >> 6;

    // Phase A: histograms (blocks 0..127)
    if (blk < SUBS) hist_body(key, hists, blk, t, (int*)shmem);
    grid.sync();

    // Phase B: scan + scatter (blocks 0..127)
    if (blk < SUBS) scatter_body(key, hists, cell_start, sorted, blk, t,
                                 (int*)shmem, (int*)shmem + 128);
    grid.sync();

    // Phase C: queries — QPW per wave
    unsigned int* wbm = shmem + wv * 256;
    #pragma unroll
    for (int qi = 0; qi < QPW; ++qi) {
        const int q = blk * (4 * QPW) + wv * QPW + qi;
        query_body(query, sorted, cell_start, out, q, lane, wbm);
    }
}

// ---------------- standalone fallback kernels (R5 pipeline) ----------------
__global__ __launch_bounds__(256) void hist_kernel(
    const float* __restrict__ key, int* __restrict__ hists)
{
    __shared__ int h[NCELL];
    hist_body(key, hists, blockIdx.x, threadIdx.x, h);
}

__global__ __launch_bounds__(256) void scatter_kernel(
    const float* __restrict__ key, const int* __restrict__ hists,
    int* __restrict__ cell_start, float4* __restrict__ sorted)
{
    __shared__ int sbuf[128];
    __shared__ int cursor[NCELL];
    scatter_body(key, hists, cell_start, sorted, blockIdx.x, threadIdx.x,
                 sbuf, cursor);
}

__global__ __launch_bounds__(256) void ballquery_grid_kernel(
    const float* __restrict__ query, const float4* __restrict__ sorted,
    const int* __restrict__ cell_start, int* __restrict__ out)
{
    __shared__ unsigned int bm[4 * 256];
    const int lane = threadIdx.x & 63;
    const int wv   = threadIdx.x >> 6;
    const int q    = blockIdx.x * 4 + wv;
    query_body(query, sorted, cell_start, out, q, lane, bm + wv * 256);
}

__global__ __launch_bounds__(256) void ballquery_bruteforce_kernel(
    const float* __restrict__ query, const float* __restrict__ key,
    int* __restrict__ out)
{
    const int lane = threadIdx.x & 63;
    const int q = blockIdx.x * 4 + (threadIdx.x >> 6);
    const int b = q >> 11;
    const float qx = query[q * 3], qy = query[q * 3 + 1], qz = query[q * 3 + 2];
    const float* kb = key + (size_t)b * N2 * 3;
    int* op = out + (size_t)q * K;
    int count = 0, first = 0;
    bool have_first = false;
    const unsigned long long lane_mask_lt = (lane == 0) ? 0ull : (~0ull >> (64 - lane));
    for (int c = 0; c < N2 / 64; ++c) {
        if (count >= K) break;
        const int j = (c << 6) + lane;
        const float* kp = kb + j * 3;
        const float dx = kp[0] - qx, dy = kp[1] - qy, dz = kp[2] - qz;
        const bool within = dx * dx + dy * dy + dz * dz < R2;
        const unsigned long long mask = __ballot(within);
        if (mask) {
            if (!have_first) { first = (c << 6) + __builtin_ctzll(mask); have_first = true; }
            if (within) {
                const int slot = count + __popcll(mask & lane_mask_lt);
                if (slot < K) op[slot] = j;
            }
            count += __popcll(mask);
        }
    }
    const int cnt = count < K ? count : K;
    if (cnt + lane < K) op[cnt + lane] = first;
}

extern "C" void kernel_launch(void* const* d_in, const int* in_sizes, int n_in,
                              void* d_out, int out_size, void* d_ws, size_t ws_size,
                              hipStream_t stream) {
    const float* query = (const float*)d_in[0];   // B*N1*3 floats
    const float* key   = (const float*)d_in[1];   // B*N2*3 floats
    int* out = (int*)d_out;                       // B*N1*K int32

    if (ws_size < WS_NEEDED) {
        ballquery_bruteforce_kernel<<<(B * N1) / 4, 256, 0, stream>>>(query, key, out);
        return;
    }

    float4* sorted     = (float4*)d_ws;
    int*    cell_start = (int*)((char*)d_ws + SORTED_BYTES);
    int*    hists      = (int*)((char*)d_ws + SORTED_BYTES + CS_BYTES);

    void* args[6] = { (void*)&query, (void*)&key, (void*)&out,
                      (void*)&hists, (void*)&cell_start, (void*)&sorted };
    hipError_t err = hipLaunchCooperativeKernel(
        (const void*)fused_kernel, dim3(GRID), dim3(256), args, 0, stream);

    if (err != hipSuccess) {
        // Deterministic per-environment fallback: R5 3-kernel pipeline.
        hist_kernel<<<SUBS, 256, 0, stream>>>(key, hists);
        scatter_kernel<<<SUBS, 256, 0, stream>>>(key, hists, cell_start, sorted);
        ballquery_grid_kernel<<<(B * N1) / 4, 256, 0, stream>>>(query, sorted, cell_start, out);
    }
}

// Round 7
// 93.694 us; speedup vs baseline: 3.2069x; 3.2069x over previous
//
#include <hip/hip_runtime.h>

// Ball query, fully fused: ONE kernel, ZERO cross-block dependencies.
// B=4, N1=2048 queries, N2=8192 keys, K=64, r=0.1 (cell = 0.2 = 2r).
//
// One batch's cell-sorted keys = 8192 * float4 = 128 KB -> fits in a CU's
// 160 KB LDS. Each block (256 thr, 1 block/CU, 64 blocks/batch, 32 queries
// per block) REDUNDANTLY builds the sorted copy of its batch in its own LDS:
//   1. LDS histogram of the batch's 8192 keys (32 keys/thread, LDS atomics)
//   2. Hillis-Steele scan of the 125 cell counts -> cell starts
//   3. scatter keys into LDS skey[] grouped by cell (LDS cursors)
//   4. per-wave: 8 queries; scan <=4 contiguous (x,y)-column z-runs from LDS,
//      set bits in an 8192-bit LDS bitmap keyed by ORIGINAL key index, then
//      extract the first K set bits in order (exact key-order output even
//      when >K hits; R3-R5-verified logic, now LDS-sourced).
//
// No workspace, no global intermediates, no grid sync (R6 showed cg
// grid.sync costs ~100us at this scale).

constexpr int   K    = 64;
constexpr float R2   = 0.01f;   // 0.1^2
constexpr int   B    = 4;
constexpr int   N1   = 2048;
constexpr int   N2   = 8192;
constexpr int   GC   = 5;                 // grid cells per dim
constexpr int   NCELL = GC * GC * GC;     // 125
constexpr float INVCELL = 5.0f;           // 1 / 0.2
constexpr int   BLOCKS = 256;             // 1 per CU (LDS-limited anyway)
constexpr int   QPW    = 8;               // queries per wave (4 waves/block)
constexpr int   PER    = N2 / 256;        // 32 keys per thread in build

__device__ __forceinline__ int cell_of(float v) {
    int c = (int)(v * INVCELL);
    return c < 0 ? 0 : (c > GC - 1 ? GC - 1 : c);
}

__global__ __launch_bounds__(256) void ballquery_fused_kernel(
    const float* __restrict__ query,   // [B*N1, 3]
    const float* __restrict__ key,     // [B*N2, 3]
    int* __restrict__ out)             // [B*N1, K]
{
    __shared__ float4 skey[N2];               // 128 KB: batch keys, cell-sorted
    __shared__ int    hist[NCELL];            // counts, then scatter cursors
    __shared__ int    sbuf[128];              // scan buffer
    __shared__ int    start[NCELL + 1];       // cell starts
    __shared__ unsigned int bm[4 * 256];      // 4 waves x 8192-bit hit bitmap

    const int blk  = blockIdx.x;
    const int b    = blk >> 6;                // 64 blocks per batch
    const int t    = threadIdx.x;
    const int lane = t & 63;
    const int wv   = t >> 6;

    // ---------- 1. histogram ----------
    if (t < NCELL) hist[t] = 0;
    __syncthreads();

    const float* kb = key + (size_t)b * N2 * 3;
    int mycell[PER];
    #pragma unroll
    for (int r = 0; r < PER; ++r) {
        const int i = r * 256 + t;            // coalesced: 12 B/lane stride
        const float x = kb[i * 3 + 0];
        const float y = kb[i * 3 + 1];
        const float z = kb[i * 3 + 2];
        const int cell = (cell_of(x) * GC + cell_of(y)) * GC + cell_of(z);
        mycell[r] = cell;
        atomicAdd(&hist[cell], 1);
    }
    __syncthreads();

    // ---------- 2. scan (Hillis-Steele over 128, proven in R5) ----------
    if (t < 128) sbuf[t] = (t < NCELL) ? hist[t] : 0;
    __syncthreads();
    for (int off = 1; off < 128; off <<= 1) {
        int v = 0;
        if (t < 128 && t >= off) v = sbuf[t - off];
        __syncthreads();
        if (t < 128) sbuf[t] += v;
        __syncthreads();
    }
    if (t < NCELL) start[t + 1] = sbuf[t];
    if (t == 0)    start[0] = 0;
    __syncthreads();
    if (t < NCELL) hist[t] = start[t];        // reset hist as scatter cursors
    __syncthreads();

    // ---------- 3. scatter into LDS (within-cell order arbitrary) ----------
    #pragma unroll
    for (int r = 0; r < PER; ++r) {
        const int i = r * 256 + t;
        const int pos = atomicAdd(&hist[mycell[r]], 1);
        float4 v;
        v.x = kb[i * 3 + 0];                  // L1/L2-hot reload
        v.y = kb[i * 3 + 1];
        v.z = kb[i * 3 + 2];
        v.w = __int_as_float(i);
        skey[pos] = v;
    }
    __syncthreads();

    // ---------- 4. queries: 8 per wave, candidates from LDS ----------
    unsigned int* wbm = bm + wv * 256;
    const int qbase = blk * (4 * QPW) + wv * QPW;   // 32 queries/block

    for (int qi = 0; qi < QPW; ++qi) {
        const int q = qbase + qi;

        const float qx = query[q * 3 + 0];
        const float qy = query[q * 3 + 1];
        const float qz = query[q * 3 + 2];

        // Octant of cells the ball can touch (cell = 2r: +/-1 on near side).
        const float ux = qx * INVCELL, uy = qy * INVCELL, uz = qz * INVCELL;
        const int cx = cell_of(qx), cy = cell_of(qy), cz = cell_of(qz);
        const int nx = (ux - cx < 0.5f) ? cx - 1 : cx + 1;
        const int ny = (uy - cy < 0.5f) ? cy - 1 : cy + 1;
        const int nz = (uz - cz < 0.5f) ? cz - 1 : cz + 1;
        const int xlo = max(0, min(cx, nx)), xhi = min(GC - 1, max(cx, nx));
        const int ylo = max(0, min(cy, ny)), yhi = min(GC - 1, max(cy, ny));
        const int zlo = max(0, min(cz, nz)), zhi = min(GC - 1, max(cz, nz));

        uint4 zz; zz.x = zz.y = zz.z = zz.w = 0u;
        ((uint4*)wbm)[lane] = zz;             // clear bitmap (ds_write_b128)
        __threadfence_block();

        for (int xx = xlo; xx <= xhi; ++xx) {
            for (int yy = ylo; yy <= yhi; ++yy) {
                const int colz = (xx * GC + yy) * GC;
                const int s = start[colz + zlo];
                const int e = start[colz + zhi + 1];   // z-cells contiguous
                for (int t0 = s; t0 < e; t0 += 64) {
                    const int i = t0 + lane;
                    const float4 kv = skey[min(i, e - 1)];
                    const float dx = kv.x - qx;
                    const float dy = kv.y - qy;
                    const float dz = kv.z - qz;
                    const bool within = (i < e) &&
                        (dx * dx + dy * dy + dz * dz < R2);
                    if (within) {
                        const int id = __float_as_int(kv.w);
                        atomicOr(&wbm[id >> 5], 1u << (id & 31));
                    }
                }
            }
        }
        __threadfence_block();

        // extraction: lane owns original-index range [128*lane, 128*(lane+1))
        const uint4 w = ((const uint4*)wbm)[lane];
        const int c = __popc(w.x) + __popc(w.y) + __popc(w.z) + __popc(w.w);

        int x = c;                            // inclusive wave prefix sum
        #pragma unroll
        for (int off = 1; off < 64; off <<= 1) {
            int y = __shfl_up(x, off);
            if (lane >= off) x += y;
        }
        const int base = x - c;
        const int cnt  = __shfl(x, 63);

        int fs;                               // first set bit (0 if none)
        if      (w.x) fs = __builtin_ctz(w.x);
        else if (w.y) fs = 32 + __builtin_ctz(w.y);
        else if (w.z) fs = 64 + __builtin_ctz(w.z);
        else if (w.w) fs = 96 + __builtin_ctz(w.w);
        else          fs = 0;
        int myfirst = c ? (lane << 7) + fs : 0x7fffffff;
        #pragma unroll
        for (int off = 32; off; off >>= 1)
            myfirst = min(myfirst, __shfl_xor(myfirst, off));
        const int firstIdx = (cnt == 0) ? 0 : myfirst;

        int* op = out + q * K;                // emit set bits in key order
        int slot = base;
        unsigned int wr[4] = {w.x, w.y, w.z, w.w};
        #pragma unroll
        for (int r = 0; r < 4; ++r) {
            unsigned int m = wr[r];
            const int bb = (lane << 7) + (r << 5);
            while (m) {
                const int bp = __builtin_ctz(m);
                m &= m - 1;
                if (slot < K) op[slot] = bb + bp;
                ++slot;
            }
        }

        const int kpad = cnt < K ? cnt : K;   // pad with firstIdx
        const int s2 = kpad + lane;
        if (s2 < K) op[s2] = firstIdx;
    }
}

extern "C" void kernel_launch(void* const* d_in, const int* in_sizes, int n_in,
                              void* d_out, int out_size, void* d_ws, size_t ws_size,
                              hipStream_t stream) {
    const float* query = (const float*)d_in[0];   // B*N1*3 floats
    const float* key   = (const float*)d_in[1];   // B*N2*3 floats
    int* out = (int*)d_out;                       // B*N1*K int32

    ballquery_fused_kernel<<<BLOCKS, 256, 0, stream>>>(query, key, out);
}

// Round 8
// 68.762 us; speedup vs baseline: 4.3696x; 1.3626x over previous
//
#include <hip/hip_runtime.h>

// Ball query, fully fused: ONE kernel, ZERO cross-block dependencies.
// B=4, N1=2048 queries, N2=8192 keys, K=64, r=0.1 (cell = 0.2 = 2r).
//
// One batch's cell-sorted keys = 8192 * float4 = 128 KB -> fits in a CU's
// 160 KB LDS. Each block REDUNDANTLY builds the sorted copy of its batch in
// its own LDS. R7 lesson: 4 waves/block left the build latency-exposed
// (43 us). Now: 256 blocks x 1024 thr (16 waves, 1 block/CU), 8 keys/thread,
// keys kept in registers between histogram and scatter (single global pass),
// 2 queries/wave.
//
//   1. LDS histogram of the batch's 8192 keys (8/thread, LDS atomics)
//   2. Hillis-Steele scan of the 125 cell counts -> cell starts
//   3. scatter keys (from registers) into LDS skey[] grouped by cell
//   4. per-wave: 2 queries; scan <=4 contiguous (x,y)-column z-runs from LDS,
//      set bits in an 8192-bit LDS bitmap keyed by ORIGINAL key index, then
//      extract the first K set bits in order (exact key-order output even
//      when >K hits; logic verified R3-R7).
//
// No workspace, no global intermediates, no grid sync (R6: cg grid.sync
// costs ~100us at this scale).

constexpr int   K    = 64;
constexpr float R2   = 0.01f;   // 0.1^2
constexpr int   B    = 4;
constexpr int   N1   = 2048;
constexpr int   N2   = 8192;
constexpr int   GC   = 5;                 // grid cells per dim
constexpr int   NCELL = GC * GC * GC;     // 125
constexpr float INVCELL = 5.0f;           // 1 / 0.2
constexpr int   BLOCKS  = 256;            // 1 per CU (LDS-limited)
constexpr int   THREADS = 1024;           // 16 waves
constexpr int   WAVES   = 16;
constexpr int   QPB     = (B * N1) / BLOCKS;  // 32 queries per block
constexpr int   QPW     = QPB / WAVES;        // 2 queries per wave
constexpr int   PER     = N2 / THREADS;       // 8 keys per thread in build

__device__ __forceinline__ int cell_of(float v) {
    int c = (int)(v * INVCELL);
    return c < 0 ? 0 : (c > GC - 1 ? GC - 1 : c);
}

__global__ __launch_bounds__(1024) void ballquery_fused_kernel(
    const float* __restrict__ query,   // [B*N1, 3]
    const float* __restrict__ key,     // [B*N2, 3]
    int* __restrict__ out)             // [B*N1, K]
{
    __shared__ float4 skey[N2];               // 128 KB: batch keys, cell-sorted
    __shared__ int    hist[NCELL];            // counts, then scatter cursors
    __shared__ int    sbuf[128];              // scan buffer
    __shared__ int    start[NCELL + 1];       // cell starts
    __shared__ unsigned int bm[WAVES * 256];  // 16 waves x 8192-bit hit bitmap

    const int blk  = blockIdx.x;
    const int b    = blk >> 6;                // 64 blocks per batch
    const int t    = threadIdx.x;
    const int lane = t & 63;
    const int wv   = t >> 6;

    // ---------- 1. histogram (keys held in registers) ----------
    if (t < NCELL) hist[t] = 0;
    __syncthreads();

    const float* kb = key + (size_t)b * N2 * 3;
    float kx[PER], ky[PER], kz[PER];
    int   kc[PER];
    #pragma unroll
    for (int r = 0; r < PER; ++r) {
        const int i = r * THREADS + t;        // coalesced 12 B/lane stride
        kx[r] = kb[i * 3 + 0];
        ky[r] = kb[i * 3 + 1];
        kz[r] = kb[i * 3 + 2];
        kc[r] = (cell_of(kx[r]) * GC + cell_of(ky[r])) * GC + cell_of(kz[r]);
        atomicAdd(&hist[kc[r]], 1);
    }
    __syncthreads();

    // ---------- 2. scan (Hillis-Steele over 128, proven R4-R7) ----------
    if (t < 128) sbuf[t] = (t < NCELL) ? hist[t] : 0;
    __syncthreads();
    for (int off = 1; off < 128; off <<= 1) {
        int v = 0;
        if (t < 128 && t >= off) v = sbuf[t - off];
        __syncthreads();
        if (t < 128) sbuf[t] += v;
        __syncthreads();
    }
    if (t < NCELL) start[t + 1] = sbuf[t];
    if (t == 0)    start[0] = 0;
    __syncthreads();
    if (t < NCELL) hist[t] = start[t];        // reset hist as scatter cursors
    __syncthreads();

    // ---------- 3. scatter from registers into LDS ----------
    #pragma unroll
    for (int r = 0; r < PER; ++r) {
        const int i = r * THREADS + t;
        const int pos = atomicAdd(&hist[kc[r]], 1);  // within-cell order
        float4 v;                                    // arbitrary; bitmap
        v.x = kx[r]; v.y = ky[r]; v.z = kz[r];       // restores key order
        v.w = __int_as_float(i);
        skey[pos] = v;
    }
    __syncthreads();

    // ---------- 4. queries: 2 per wave, candidates from LDS ----------
    unsigned int* wbm = bm + wv * 256;
    const int qbase = blk * QPB + wv * QPW;

    #pragma unroll
    for (int qi = 0; qi < QPW; ++qi) {
        const int q = qbase + qi;

        const float qx = query[q * 3 + 0];
        const float qy = query[q * 3 + 1];
        const float qz = query[q * 3 + 2];

        // Octant of cells the ball can touch (cell = 2r: +/-1 on near side).
        const float ux = qx * INVCELL, uy = qy * INVCELL, uz = qz * INVCELL;
        const int cx = cell_of(qx), cy = cell_of(qy), cz = cell_of(qz);
        const int nx = (ux - cx < 0.5f) ? cx - 1 : cx + 1;
        const int ny = (uy - cy < 0.5f) ? cy - 1 : cy + 1;
        const int nz = (uz - cz < 0.5f) ? cz - 1 : cz + 1;
        const int xlo = max(0, min(cx, nx)), xhi = min(GC - 1, max(cx, nx));
        const int ylo = max(0, min(cy, ny)), yhi = min(GC - 1, max(cy, ny));
        const int zlo = max(0, min(cz, nz)), zhi = min(GC - 1, max(cz, nz));

        uint4 zz; zz.x = zz.y = zz.z = zz.w = 0u;
        ((uint4*)wbm)[lane] = zz;             // clear bitmap (ds_write_b128)
        __threadfence_block();

        for (int xx = xlo; xx <= xhi; ++xx) {
            for (int yy = ylo; yy <= yhi; ++yy) {
                const int colz = (xx * GC + yy) * GC;
                const int s = start[colz + zlo];
                const int e = start[colz + zhi + 1];   // z-cells contiguous
                for (int t0 = s; t0 < e; t0 += 64) {
                    const int i = t0 + lane;
                    const float4 kv = skey[min(i, e - 1)];
                    const float dx = kv.x - qx;
                    const float dy = kv.y - qy;
                    const float dz = kv.z - qz;
                    const bool within = (i < e) &&
                        (dx * dx + dy * dy + dz * dz < R2);
                    if (within) {
                        const int id = __float_as_int(kv.w);
                        atomicOr(&wbm[id >> 5], 1u << (id & 31));
                    }
                }
            }
        }
        __threadfence_block();

        // extraction: lane owns original-index range [128*lane, 128*(lane+1))
        const uint4 w = ((const uint4*)wbm)[lane];
        const int c = __popc(w.x) + __popc(w.y) + __popc(w.z) + __popc(w.w);

        int x = c;                            // inclusive wave prefix sum
        #pragma unroll
        for (int off = 1; off < 64; off <<= 1) {
            int y = __shfl_up(x, off);
            if (lane >= off) x += y;
        }
        const int base = x - c;
        const int cnt  = __shfl(x, 63);

        int fs;                               // first set bit (0 if none)
        if      (w.x) fs = __builtin_ctz(w.x);
        else if (w.y) fs = 32 + __builtin_ctz(w.y);
        else if (w.z) fs = 64 + __builtin_ctz(w.z);
        else if (w.w) fs = 96 + __builtin_ctz(w.w);
        else          fs = 0;
        int myfirst = c ? (lane << 7) + fs : 0x7fffffff;
        #pragma unroll
        for (int off = 32; off; off >>= 1)
            myfirst = min(myfirst, __shfl_xor(myfirst, off));
        const int firstIdx = (cnt == 0) ? 0 : myfirst;

        int* op = out + q * K;                // emit set bits in key order
        int slot = base;
        unsigned int wr[4] = {w.x, w.y, w.z, w.w};
        #pragma unroll
        for (int r = 0; r < 4; ++r) {
            unsigned int m = wr[r];
            const int bb = (lane << 7) + (r << 5);
            while (m) {
                const int bp = __builtin_ctz(m);
                m &= m - 1;
                if (slot < K) op[slot] = bb + bp;
                ++slot;
            }
        }

        const int kpad = cnt < K ? cnt : K;   // pad with firstIdx
        const int s2 = kpad + lane;
        if (s2 < K) op[s2] = firstIdx;
    }
}

extern "C" void kernel_launch(void* const* d_in, const int* in_sizes, int n_in,
                              void* d_out, int out_size, void* d_ws, size_t ws_size,
                              hipStream_t stream) {
    const float* query = (const float*)d_in[0];   // B*N1*3 floats
    const float* key   = (const float*)d_in[1];   // B*N2*3 floats
    int* out = (int*)d_out;                       // B*N1*K int32

    ballquery_fused_kernel<<<BLOCKS, THREADS, 0, stream>>>(query, key, out);
}